// Round 1
// baseline (236.629 us; speedup 1.0000x reference)
//
#include <hip/hip_runtime.h>
#include <math.h>

#define B_ 32
#define S_ 4096
#define H_ 1024
#define NBLK 64                      // pass1 blocks per batch
#define ROWS_PER_BLOCK (S_ / NBLK)   // 64
#define ROWS_PER_WAVE  (ROWS_PER_BLOCK / 4)  // 16

__device__ __forceinline__ float wave_reduce_sum(float v) {
    #pragma unroll
    for (int o = 32; o > 0; o >>= 1) v += __shfl_xor(v, o, 64);
    return v;
}

// y[b*ystride + i] = sum_j x[b*xstride + j] * W[i*H + j] + bias[i]
// one wave per (b,i); grid = B*H/4 blocks of 256
__global__ __launch_bounds__(256) void gemv_aw(const float* __restrict__ x, int xstride,
                                               const float* __restrict__ W,
                                               const float* __restrict__ bias,
                                               float* __restrict__ y, int ystride) {
    int w = threadIdx.x >> 6, lane = threadIdx.x & 63;
    int gw = blockIdx.x * 4 + w;            // [0, B*H)
    int b = gw >> 10, i = gw & 1023;
    const float4* xr = reinterpret_cast<const float4*>(x + (size_t)b * xstride);
    const float4* wr = reinterpret_cast<const float4*>(W + (size_t)i * H_);
    float s = 0.f;
    #pragma unroll
    for (int k = 0; k < 4; ++k) {
        float4 a = xr[lane + k * 64];
        float4 ww = wr[lane + k * 64];
        s += a.x * ww.x + a.y * ww.y + a.z * ww.z + a.w * ww.w;
    }
    s = wave_reduce_sum(s);
    if (lane == 0) y[(size_t)b * ystride + i] = s + bias[i];
}

// Flash-style single pass over encoder_outputs.
// Per block: 4 waves, each owns ROWS_PER_WAVE rows; online softmax + ctx accum
// in registers; wave partials combined in LDS; per-block partial -> ws.
__global__ __launch_bounds__(256) void attn_pass1(const float* __restrict__ enc,
                                                  const float* __restrict__ h2,
                                                  float* __restrict__ scores,
                                                  float* __restrict__ partials) {
    int b   = blockIdx.x / NBLK;
    int blk = blockIdx.x % NBLK;
    int w = threadIdx.x >> 6, lane = threadIdx.x & 63;

    const float4* hp = reinterpret_cast<const float4*>(h2 + (size_t)b * H_);
    float4 hv[4];
    #pragma unroll
    for (int k = 0; k < 4; ++k) hv[k] = hp[lane + k * 64];

    float m = -INFINITY, l = 0.f;
    float4 acc[4];
    #pragma unroll
    for (int k = 0; k < 4; ++k) acc[k] = make_float4(0.f, 0.f, 0.f, 0.f);

    int row0 = blk * ROWS_PER_BLOCK + w * ROWS_PER_WAVE;
    const float* encb = enc + (size_t)b * S_ * H_;
    float my_score = 0.f;  // lane r keeps row (row0+r)'s score for a coalesced store

    for (int r = 0; r < ROWS_PER_WAVE; ++r) {
        int row = row0 + r;
        const float4* rp = reinterpret_cast<const float4*>(encb + (size_t)row * H_);
        float4 v[4];
        #pragma unroll
        for (int k = 0; k < 4; ++k) v[k] = rp[lane + k * 64];
        float s = 0.f;
        #pragma unroll
        for (int k = 0; k < 4; ++k)
            s += v[k].x * hv[k].x + v[k].y * hv[k].y + v[k].z * hv[k].z + v[k].w * hv[k].w;
        s = wave_reduce_sum(s);
        my_score = (lane == r) ? s : my_score;

        float nm = fmaxf(m, s);
        float scale = __expf(m - nm);   // m=-inf first iter -> 0, safe
        float p = __expf(s - nm);
        l = l * scale + p;
        #pragma unroll
        for (int k = 0; k < 4; ++k) {
            acc[k].x = acc[k].x * scale + p * v[k].x;
            acc[k].y = acc[k].y * scale + p * v[k].y;
            acc[k].z = acc[k].z * scale + p * v[k].z;
            acc[k].w = acc[k].w * scale + p * v[k].w;
        }
        m = nm;
    }
    if (lane < ROWS_PER_WAVE) scores[(size_t)b * S_ + row0 + lane] = my_score;

    // combine 4 waves in LDS
    __shared__ float lds_ctx[4][H_];
    __shared__ float lds_m[4], lds_l[4];
    float4* lc = reinterpret_cast<float4*>(&lds_ctx[w][0]);
    #pragma unroll
    for (int k = 0; k < 4; ++k) lc[lane + k * 64] = acc[k];
    if (lane == 0) { lds_m[w] = m; lds_l[w] = l; }
    __syncthreads();

    float mb = fmaxf(fmaxf(lds_m[0], lds_m[1]), fmaxf(lds_m[2], lds_m[3]));
    float sc0 = __expf(lds_m[0] - mb), sc1 = __expf(lds_m[1] - mb);
    float sc2 = __expf(lds_m[2] - mb), sc3 = __expf(lds_m[3] - mb);
    float lb = lds_l[0] * sc0 + lds_l[1] * sc1 + lds_l[2] * sc2 + lds_l[3] * sc3;

    float* part = partials + ((size_t)b * NBLK + blk) * (H_ + 2);
    #pragma unroll
    for (int k = 0; k < 4; ++k) {
        int col = threadIdx.x + k * 256;
        float v = lds_ctx[0][col] * sc0 + lds_ctx[1][col] * sc1 +
                  lds_ctx[2][col] * sc2 + lds_ctx[3][col] * sc3;
        part[2 + col] = v;
    }
    if (threadIdx.x == 0) { part[0] = mb; part[1] = lb; }
}

// per-batch reduce of NBLK partials -> context (normalized) + (m, l) stats
__global__ __launch_bounds__(256) void attn_reduce(const float* __restrict__ partials,
                                                   float* __restrict__ concat,
                                                   float* __restrict__ stats) {
    int b = blockIdx.x;
    const float* part = partials + (size_t)b * NBLK * (H_ + 2);
    __shared__ float sm[NBLK], sl[NBLK], ssc[NBLK];
    int t = threadIdx.x;
    if (t < NBLK) {
        sm[t] = part[(size_t)t * (H_ + 2)];
        sl[t] = part[(size_t)t * (H_ + 2) + 1];
    }
    __syncthreads();
    float mb = -INFINITY;
    #pragma unroll
    for (int k = 0; k < NBLK; ++k) mb = fmaxf(mb, sm[k]);
    if (t < NBLK) ssc[t] = __expf(sm[t] - mb);
    __syncthreads();
    float lb = 0.f;
    #pragma unroll
    for (int k = 0; k < NBLK; ++k) lb += sl[k] * ssc[k];
    float inv_l = 1.f / lb;
    #pragma unroll
    for (int k2 = 0; k2 < 4; ++k2) {
        int col = t + k2 * 256;
        float v = 0.f;
        #pragma unroll
        for (int k = 0; k < NBLK; ++k)
            v += part[(size_t)k * (H_ + 2) + 2 + col] * ssc[k];
        concat[(size_t)b * 2048 + 1024 + col] = v * inv_l;
    }
    if (t == 0) { stats[2 * b] = mb; stats[2 * b + 1] = lb; }
}

__global__ __launch_bounds__(256) void attn_write(const float* __restrict__ scores,
                                                  const float* __restrict__ stats,
                                                  float* __restrict__ attn_out) {
    int idx = blockIdx.x * 256 + threadIdx.x;   // [0, B*S)
    int b = idx >> 12;                          // /4096
    float m = stats[2 * b], l = stats[2 * b + 1];
    attn_out[idx] = __expf(scores[idx] - m) / l;
}

// out[b,i] = tanh(sum_j concat[b,j] * Cw[i*2048+j] + Cb[i]); one wave per i,
// Cw row held in registers, looped over all 32 batches (concat is L2-hot).
__global__ __launch_bounds__(256) void out_gemm(const float* __restrict__ concat,
                                                const float* __restrict__ Cw,
                                                const float* __restrict__ Cb,
                                                float* __restrict__ out) {
    int w = threadIdx.x >> 6, lane = threadIdx.x & 63;
    int i = blockIdx.x * 4 + w;                 // [0, 1024)
    const float4* wr = reinterpret_cast<const float4*>(Cw + (size_t)i * 2048);
    float4 wv[8];
    #pragma unroll
    for (int k = 0; k < 8; ++k) wv[k] = wr[lane + k * 64];
    float bias = Cb[i];
    for (int b = 0; b < B_; ++b) {
        const float4* cr = reinterpret_cast<const float4*>(concat + (size_t)b * 2048);
        float s = 0.f;
        #pragma unroll
        for (int k = 0; k < 8; ++k) {
            float4 c = cr[lane + k * 64];
            s += c.x * wv[k].x + c.y * wv[k].y + c.z * wv[k].z + c.w * wv[k].w;
        }
        s = wave_reduce_sum(s);
        if (lane == 0) out[(size_t)b * H_ + i] = tanhf(s + bias);
    }
}

extern "C" void kernel_launch(void* const* d_in, const int* in_sizes, int n_in,
                              void* d_out, int out_size, void* d_ws, size_t ws_size,
                              hipStream_t stream) {
    const float* hs  = (const float*)d_in[0];   // [B,1,H]
    const float* enc = (const float*)d_in[1];   // [B,S,H]
    const float* A_w = (const float*)d_in[2];   // [H,H]
    const float* A_b = (const float*)d_in[3];   // [H]
    const float* C_w = (const float*)d_in[4];   // [H,2H]
    const float* C_b = (const float*)d_in[5];   // [H]

    float* out      = (float*)d_out;            // [B,H] first
    float* attn_out = out + B_ * H_;            // then [B,S,1]

    // workspace layout (floats)
    float* ws       = (float*)d_ws;
    float* concat   = ws;                                   // [B][2048]: h1 | ctx
    float* h2       = ws + (size_t)B_ * 2048;               // [B][1024]
    float* scores   = h2 + (size_t)B_ * H_;                 // [B][S]
    float* partials = scores + (size_t)B_ * S_;             // [B][NBLK][H+2]
    float* stats    = partials + (size_t)B_ * NBLK * (H_ + 2);  // [B][2]

    // h1 -> concat[:, 0:1024]
    gemv_aw<<<(B_ * H_) / 4, 256, 0, stream>>>(hs, H_, A_w, A_b, concat, 2048);
    // h2 = A(h1)
    gemv_aw<<<(B_ * H_) / 4, 256, 0, stream>>>(concat, 2048, A_w, A_b, h2, H_);
    // flash pass over enc (the 512 MB read)
    attn_pass1<<<B_ * NBLK, 256, 0, stream>>>(enc, h2, scores, partials);
    // combine per-batch partials -> context into concat[:, 1024:2048]
    attn_reduce<<<B_, 256, 0, stream>>>(partials, concat, stats);
    // normalized attention weights -> output
    attn_write<<<(B_ * S_) / 256, 256, 0, stream>>>(scores, stats, attn_out);
    // final projection + tanh
    out_gemm<<<H_ / 4, 256, 0, stream>>>(concat, C_w, C_b, out);
}

// Round 2
// 143.493 us; speedup vs baseline: 1.6491x; 1.6491x over previous
//
#include <hip/hip_runtime.h>
#include <math.h>

#define B_ 32
#define S_ 4096
#define H_ 1024

// ---- pass1 geometry ----
#define TROWS 8                 // rows per LDS tile (32 KB)
#define RPB   128               // rows per block
#define NT    (RPB / TROWS)     // 16 tiles per block
#define NBLK  (S_ / RPB)        // 32 blocks per batch

__device__ __forceinline__ float wave_reduce_sum(float v) {
    #pragma unroll
    for (int o = 32; o > 0; o >>= 1) v += __shfl_xor(v, o, 64);
    return v;
}

// y[b*ystride + i] = sum_j x[b*xstride + j] * W[i*H + j] + bias[i]
__global__ __launch_bounds__(256) void gemv_aw(const float* __restrict__ x, int xstride,
                                               const float* __restrict__ W,
                                               const float* __restrict__ bias,
                                               float* __restrict__ y, int ystride) {
    int w = threadIdx.x >> 6, lane = threadIdx.x & 63;
    int gw = blockIdx.x * 4 + w;            // [0, B*H)
    int b = gw >> 10, i = gw & 1023;
    const float4* xr = reinterpret_cast<const float4*>(x + (size_t)b * xstride);
    const float4* wr = reinterpret_cast<const float4*>(W + (size_t)i * H_);
    float s = 0.f;
    #pragma unroll
    for (int k = 0; k < 4; ++k) {
        float4 a = xr[lane + k * 64];
        float4 ww = wr[lane + k * 64];
        s += a.x * ww.x + a.y * ww.y + a.z * ww.z + a.w * ww.w;
    }
    s = wave_reduce_sum(s);
    if (lane == 0) y[(size_t)b * ystride + i] = s + bias[i];
}

// Flash pass over enc, LDS double-buffered: streaming loads decoupled from the
// online-softmax dependency chain. 4 waves, each owns 2 rows per 8-row tile.
__global__ __launch_bounds__(256, 2) void attn_pass1(const float* __restrict__ enc,
                                                     const float* __restrict__ h2,
                                                     float* __restrict__ scores,
                                                     float* __restrict__ partials) {
    int b   = blockIdx.x >> 5;              // NBLK = 32 blocks per batch
    int blk = blockIdx.x & (NBLK - 1);
    int w = threadIdx.x >> 6, lane = threadIdx.x & 63;

    __shared__ float lds[2][TROWS][H_];     // 64 KB
    __shared__ float lds_m[4], lds_l[4];

    const float* encb = enc + (size_t)b * S_ * H_ + (size_t)blk * RPB * H_;

    const float4* hp = reinterpret_cast<const float4*>(h2 + (size_t)b * H_);
    float4 hv[4];
    #pragma unroll
    for (int k = 0; k < 4; ++k) hv[k] = hp[lane + k * 64];

    float m = -INFINITY, l = 0.f;
    float4 acc[4];
    #pragma unroll
    for (int k = 0; k < 4; ++k) acc[k] = make_float4(0.f, 0.f, 0.f, 0.f);

    const int c0 = w * 8;                   // this wave's 8 staging chunks
    float4 stg[8];

    // prologue: stage tile 0 into buf 0
    #pragma unroll
    for (int i = 0; i < 8; ++i) {
        int c = c0 + i;
        stg[i] = *reinterpret_cast<const float4*>(
            encb + (size_t)(c >> 2) * H_ + (c & 3) * 256 + lane * 4);
    }
    #pragma unroll
    for (int i = 0; i < 8; ++i) {
        int c = c0 + i;
        *reinterpret_cast<float4*>(&lds[0][c >> 2][(c & 3) * 256 + lane * 4]) = stg[i];
    }
    __syncthreads();

    int cur = 0;
    for (int t = 0; t < NT; ++t) {
        // issue next tile's global loads FIRST (stay in flight across compute)
        if (t + 1 < NT) {
            #pragma unroll
            for (int i = 0; i < 8; ++i) {
                int c = c0 + i;
                stg[i] = *reinterpret_cast<const float4*>(
                    encb + (size_t)((t + 1) * TROWS + (c >> 2)) * H_ + (c & 3) * 256 + lane * 4);
            }
        }
        // compute this wave's two rows from LDS
        float4 v0[4], v1[4];
        #pragma unroll
        for (int k = 0; k < 4; ++k)
            v0[k] = *reinterpret_cast<const float4*>(&lds[cur][w * 2    ][k * 256 + lane * 4]);
        #pragma unroll
        for (int k = 0; k < 4; ++k)
            v1[k] = *reinterpret_cast<const float4*>(&lds[cur][w * 2 + 1][k * 256 + lane * 4]);

        float s0 = 0.f, s1 = 0.f;
        #pragma unroll
        for (int k = 0; k < 4; ++k) {
            s0 += v0[k].x * hv[k].x + v0[k].y * hv[k].y + v0[k].z * hv[k].z + v0[k].w * hv[k].w;
            s1 += v1[k].x * hv[k].x + v1[k].y * hv[k].y + v1[k].z * hv[k].z + v1[k].w * hv[k].w;
        }
        s0 = wave_reduce_sum(s0);           // two independent chains overlap
        s1 = wave_reduce_sum(s1);

        int row = blk * RPB + t * TROWS + w * 2;
        if (lane == 0) {
            scores[(size_t)b * S_ + row]     = s0;
            scores[(size_t)b * S_ + row + 1] = s1;
        }

        float tm = fmaxf(s0, s1);
        if (tm > m) {                       // wave-uniform, rare (~ln(256) times)
            float scale = __expf(m - tm);   // m=-inf first time -> 0, exact
            l *= scale;
            #pragma unroll
            for (int k = 0; k < 4; ++k) {
                acc[k].x *= scale; acc[k].y *= scale;
                acc[k].z *= scale; acc[k].w *= scale;
            }
            m = tm;
        }
        float p0 = __expf(s0 - m), p1 = __expf(s1 - m);
        l += p0 + p1;
        #pragma unroll
        for (int k = 0; k < 4; ++k) {
            acc[k].x += p0 * v0[k].x + p1 * v1[k].x;
            acc[k].y += p0 * v0[k].y + p1 * v1[k].y;
            acc[k].z += p0 * v0[k].z + p1 * v1[k].z;
            acc[k].w += p0 * v0[k].w + p1 * v1[k].w;
        }
        // write staged regs into the other LDS buffer
        if (t + 1 < NT) {
            #pragma unroll
            for (int i = 0; i < 8; ++i) {
                int c = c0 + i;
                *reinterpret_cast<float4*>(&lds[cur ^ 1][c >> 2][(c & 3) * 256 + lane * 4]) = stg[i];
            }
        }
        __syncthreads();
        cur ^= 1;
    }

    // 4-wave merge; reuse lds[0] rows 0..3 as context scratch
    float* mc = &lds[0][w][0];
    #pragma unroll
    for (int k = 0; k < 4; ++k)
        *reinterpret_cast<float4*>(&mc[k * 256 + lane * 4]) = acc[k];
    if (lane == 0) { lds_m[w] = m; lds_l[w] = l; }
    __syncthreads();

    float mb = fmaxf(fmaxf(lds_m[0], lds_m[1]), fmaxf(lds_m[2], lds_m[3]));
    float sc0 = __expf(lds_m[0] - mb), sc1 = __expf(lds_m[1] - mb);
    float sc2 = __expf(lds_m[2] - mb), sc3 = __expf(lds_m[3] - mb);
    float lb = lds_l[0] * sc0 + lds_l[1] * sc1 + lds_l[2] * sc2 + lds_l[3] * sc3;

    float* part = partials + ((size_t)b * NBLK + blk) * (H_ + 2);
    #pragma unroll
    for (int k2 = 0; k2 < 4; ++k2) {
        int col = threadIdx.x + k2 * 256;
        float v = lds[0][0][col] * sc0 + lds[0][1][col] * sc1 +
                  lds[0][2][col] * sc2 + lds[0][3][col] * sc3;
        part[2 + col] = v;
    }
    if (threadIdx.x == 0) { part[0] = mb; part[1] = lb; }
}

// per-batch reduce of NBLK partials -> normalized context + (m,l) stats
// grid = B*4 blocks; each block handles 256 cols of one batch
__global__ __launch_bounds__(256) void attn_reduce(const float* __restrict__ partials,
                                                   float* __restrict__ concat,
                                                   float* __restrict__ stats) {
    int b = blockIdx.x >> 2;
    int q = blockIdx.x & 3;
    const float* part = partials + (size_t)b * NBLK * (H_ + 2);
    float ms[NBLK];
    float mb = -INFINITY;
    #pragma unroll
    for (int k = 0; k < NBLK; ++k) {
        ms[k] = part[(size_t)k * (H_ + 2)];
        mb = fmaxf(mb, ms[k]);
    }
    float lb = 0.f;
    float sc[NBLK];
    #pragma unroll
    for (int k = 0; k < NBLK; ++k) {
        sc[k] = __expf(ms[k] - mb);
        lb += part[(size_t)k * (H_ + 2) + 1] * sc[k];
    }
    int col = q * 256 + threadIdx.x;
    float v = 0.f;
    #pragma unroll
    for (int k = 0; k < NBLK; ++k)
        v += part[(size_t)k * (H_ + 2) + 2 + col] * sc[k];
    concat[(size_t)b * 2048 + 1024 + col] = v / lb;
    if (q == 0 && threadIdx.x == 0) { stats[2 * b] = mb; stats[2 * b + 1] = lb; }
}

__global__ __launch_bounds__(256) void attn_write(const float* __restrict__ scores,
                                                  const float* __restrict__ stats,
                                                  float* __restrict__ attn_out) {
    int idx = blockIdx.x * 256 + threadIdx.x;   // [0, B*S)
    int b = idx >> 12;                          // /4096
    float m = stats[2 * b], l = stats[2 * b + 1];
    attn_out[idx] = __expf(scores[idx] - m) / l;
}

// out[b,i] = tanh(dot(concat[b,:], Cw[i,:]) + Cb[i])
// one block per i; 4 waves each handle 8 batches (concat L2-hot)
__global__ __launch_bounds__(256) void out_gemm(const float* __restrict__ concat,
                                                const float* __restrict__ Cw,
                                                const float* __restrict__ Cb,
                                                float* __restrict__ out) {
    int w = threadIdx.x >> 6, lane = threadIdx.x & 63;
    int i = blockIdx.x;
    const float4* wr = reinterpret_cast<const float4*>(Cw + (size_t)i * 2048);
    float4 wv[8];
    #pragma unroll
    for (int k = 0; k < 8; ++k) wv[k] = wr[lane + k * 64];
    float bias = Cb[i];
    #pragma unroll
    for (int bb = 0; bb < 8; ++bb) {
        int b = w * 8 + bb;
        const float4* cr = reinterpret_cast<const float4*>(concat + (size_t)b * 2048);
        float s = 0.f;
        #pragma unroll
        for (int k = 0; k < 8; ++k) {
            float4 c = cr[lane + k * 64];
            s += c.x * wv[k].x + c.y * wv[k].y + c.z * wv[k].z + c.w * wv[k].w;
        }
        s = wave_reduce_sum(s);
        if (lane == 0) out[(size_t)b * H_ + i] = tanhf(s + bias);
    }
}

extern "C" void kernel_launch(void* const* d_in, const int* in_sizes, int n_in,
                              void* d_out, int out_size, void* d_ws, size_t ws_size,
                              hipStream_t stream) {
    const float* hs  = (const float*)d_in[0];   // [B,1,H]
    const float* enc = (const float*)d_in[1];   // [B,S,H]
    const float* A_w = (const float*)d_in[2];   // [H,H]
    const float* A_b = (const float*)d_in[3];   // [H]
    const float* C_w = (const float*)d_in[4];   // [H,2H]
    const float* C_b = (const float*)d_in[5];   // [H]

    float* out      = (float*)d_out;            // [B,H] first
    float* attn_out = out + B_ * H_;            // then [B,S,1]

    // workspace layout (floats)
    float* ws       = (float*)d_ws;
    float* concat   = ws;                                   // [B][2048]: h1 | ctx
    float* h2       = ws + (size_t)B_ * 2048;               // [B][1024]
    float* scores   = h2 + (size_t)B_ * H_;                 // [B][S]
    float* partials = scores + (size_t)B_ * S_;             // [B][NBLK][H+2]
    float* stats    = partials + (size_t)B_ * NBLK * (H_ + 2);  // [B][2]

    gemv_aw<<<(B_ * H_) / 4, 256, 0, stream>>>(hs, H_, A_w, A_b, concat, 2048);
    gemv_aw<<<(B_ * H_) / 4, 256, 0, stream>>>(concat, 2048, A_w, A_b, h2, H_);
    attn_pass1<<<B_ * NBLK, 256, 0, stream>>>(enc, h2, scores, partials);
    attn_reduce<<<B_ * 4, 256, 0, stream>>>(partials, concat, stats);
    attn_write<<<(B_ * S_) / 256, 256, 0, stream>>>(scores, stats, attn_out);
    out_gemm<<<H_, 256, 0, stream>>>(concat, C_w, C_b, out);
}